// Round 8
// baseline (264.050 us; speedup 1.0000x reference)
//
#include <hip/hip_runtime.h>

#define D 128
#define BSH 9
#define BW 512

typedef __attribute__((ext_vector_type(8))) short bf16x8;
typedef __attribute__((ext_vector_type(4))) float f32x4;

__device__ __forceinline__ unsigned int f2bf(float x) {
    unsigned int u = __float_as_uint(x);
    return (u + 0x7FFFu + ((u >> 16) & 1u)) >> 16;   // RNE
}

// per-bucket histograms of dst AND src (bucket = id>>9)
__global__ __launch_bounds__(256) void k_count(
        const int* __restrict__ src, const int* __restrict__ dst,
        int* __restrict__ bcntD, int* __restrict__ bcntS, int nE, int NBK) {
    __shared__ int lhD[256], lhS[256];
    int t = threadIdx.x;
    lhD[t] = 0; lhS[t] = 0;
    __syncthreads();
    int base = blockIdx.x * 4096;
    #pragma unroll
    for (int i = 0; i < 16; ++i) {
        int e = base + i * 256 + t;
        if (e < nE) {
            atomicAdd(&lhD[dst[e] >> BSH], 1);
            atomicAdd(&lhS[src[e] >> BSH], 1);
        }
    }
    __syncthreads();
    if (t < NBK) {
        if (lhD[t]) atomicAdd(&bcntD[t], lhD[t]);
        if (lhS[t]) atomicAdd(&bcntS[t], lhS[t]);
    }
}

__global__ __launch_bounds__(256) void k_bscan2(
        const int* __restrict__ bcntD, const int* __restrict__ bcntS,
        int* __restrict__ bbaseD, int* __restrict__ bcurD,
        int* __restrict__ bbaseS, int* __restrict__ bcurS, int NBK, int nE) {
    __shared__ int sh[256];
    int t = threadIdx.x;
    sh[t] = (t < NBK) ? bcntD[t] : 0;
    __syncthreads();
    for (int off = 1; off < 256; off <<= 1) {
        int u = (t >= off) ? sh[t - off] : 0;
        __syncthreads();
        sh[t] += u;
        __syncthreads();
    }
    if (t < NBK) {
        int excl = (t == 0) ? 0 : sh[t - 1];
        bbaseD[t] = excl; bcurD[t] = excl;
    }
    if (t == 0) bbaseD[NBK] = nE;
    __syncthreads();
    sh[t] = (t < NBK) ? bcntS[t] : 0;
    __syncthreads();
    for (int off = 1; off < 256; off <<= 1) {
        int u = (t >= off) ? sh[t - off] : 0;
        __syncthreads();
        sh[t] += u;
        __syncthreads();
    }
    if (t < NBK) {
        int excl = (t == 0) ? 0 : sh[t - 1];
        bbaseS[t] = excl; bcurS[t] = excl;
    }
    if (t == 0) bbaseS[NBK] = nE;
}

__global__ __launch_bounds__(256) void k_pairs(
        const int* __restrict__ src, const int* __restrict__ dst,
        int* __restrict__ bcurD, int* __restrict__ bcurS,
        unsigned int* __restrict__ pairsD, unsigned short* __restrict__ srcL,
        int nE) {
    __shared__ int lhD[256], lcD[256], lhS[256], lcS[256];
    int t = threadIdx.x;
    lhD[t] = 0; lhS[t] = 0;
    __syncthreads();
    int base = blockIdx.x * 4096;
    #pragma unroll
    for (int i = 0; i < 16; ++i) {
        int e = base + i * 256 + t;
        if (e < nE) {
            atomicAdd(&lhD[dst[e] >> BSH], 1);
            atomicAdd(&lhS[src[e] >> BSH], 1);
        }
    }
    __syncthreads();
    int cD = lhD[t];
    lcD[t] = cD ? atomicAdd(&bcurD[t], cD) : 0;
    int cS = lhS[t];
    lcS[t] = cS ? atomicAdd(&bcurS[t], cS) : 0;
    __syncthreads();
    #pragma unroll
    for (int i = 0; i < 16; ++i) {
        int e = base + i * 256 + t;
        if (e < nE) {
            int s = src[e], d = dst[e];
            int pD = atomicAdd(&lcD[d >> BSH], 1);
            pairsD[pD] = ((unsigned)s << BSH) | (unsigned)(d & (BW - 1));
            int pS = atomicAdd(&lcS[s >> BSH], 1);
            srcL[pS] = (unsigned short)(s & (BW - 1));
        }
    }
}

__global__ __launch_bounds__(512) void k_binD(
        const unsigned int* __restrict__ pairsD, const int* __restrict__ bbaseD,
        int* __restrict__ degI, int* __restrict__ offs,
        int* __restrict__ elist, int nN) {
    __shared__ int c0[BW], sh[BW], lcur[BW];
    int b = blockIdx.x, t = threadIdx.x;
    int p0 = bbaseD[b], p1 = bbaseD[b + 1];
    int n0 = b << BSH;
    c0[t] = 0;
    __syncthreads();
    for (int j = p0 + t; j < p1; j += 512)
        atomicAdd(&c0[pairsD[j] & (BW - 1u)], 1);
    __syncthreads();
    sh[t] = c0[t];
    __syncthreads();
    for (int off = 1; off < BW; off <<= 1) {
        int u = (t >= off) ? sh[t - off] : 0;
        __syncthreads();
        sh[t] += u;
        __syncthreads();
    }
    int excl = (t == 0) ? 0 : sh[t - 1];
    int node = n0 + t;
    if (node < nN) { degI[node] = c0[t]; offs[node] = p0 + excl; }
    lcur[t] = p0 + excl;
    __syncthreads();
    for (int j = p0 + t; j < p1; j += 512) {
        unsigned int pr = pairsD[j];
        int pos = atomicAdd(&lcur[pr & (BW - 1u)], 1);
        elist[pos] = (int)(pr >> BSH);
    }
}

__global__ __launch_bounds__(512) void k_binO(
        const unsigned short* __restrict__ srcL, const int* __restrict__ bbaseS,
        int* __restrict__ degO, int nN) {
    __shared__ int c0[BW];
    int b = blockIdx.x, t = threadIdx.x;
    int p0 = bbaseS[b], p1 = bbaseS[b + 1];
    c0[t] = 0;
    __syncthreads();
    for (int j = p0 + t; j < p1; j += 512)
        atomicAdd(&c0[srcL[j]], 1);
    __syncthreads();
    int node = (b << BSH) + t;
    if (node < nN) degO[node] = c0[t];
}

__global__ __launch_bounds__(256) void k_prep2(
        const float* __restrict__ heat, const int* __restrict__ degO,
        unsigned short* __restrict__ heatS, int nN) {
    int i = blockIdx.x * 256 + threadIdx.x;
    if (i >= nN * 32) return;
    int node = i >> 5;
    int c4 = (i & 31) << 2;
    float4 v = *reinterpret_cast<const float4*>(heat + ((size_t)node << 7) + c4);
    float sc = rsqrtf((float)max(degO[node], 1));
    unsigned int b0 = f2bf(v.x * sc), b1 = f2bf(v.y * sc);
    unsigned int b2 = f2bf(v.z * sc), b3 = f2bf(v.w * sc);
    uint2 p = make_uint2(b0 | (b1 << 16), b2 | (b3 << 16));
    *reinterpret_cast<uint2*>(heatS + ((size_t)node << 7) + c4) = p;
}

// W -> bf16, transposed: WtB[c*128 + k] = bf16(W[k*128 + c])
__global__ __launch_bounds__(256) void k_prepW(
        const float* __restrict__ W, unsigned short* __restrict__ WtB) {
    int idx = blockIdx.x * 256 + threadIdx.x;
    if (idx >= D * D) return;
    int k = idx >> 7, c = idx & 127;
    WtB[c * D + k] = (unsigned short)f2bf(W[idx]);
}

// fused gather (global->LDS bf16) + MFMA gemm + epilogue + stats
#define BM 64
__global__ __launch_bounds__(256, 4) void k_fused(
        const unsigned short* __restrict__ heatS, const int* __restrict__ elist,
        const int* __restrict__ offs, const int* __restrict__ degI,
        const unsigned short* __restrict__ WtB, const float* __restrict__ b,
        const float* __restrict__ a1, float* __restrict__ h,
        float* __restrict__ sums, float* __restrict__ sumsq, int nN) {
    __shared__ unsigned short sA[BM * 136];     // 64 rows, 136-pad (conflict-free b128)
    __shared__ float ss1[128], ss2[128];
    int t = threadIdx.x;
    int w = t >> 6, l = t & 63;
    int lg = l >> 4;          // edge subgroup 0..3
    int lc = l & 15;          // col group: cols 8*lc .. 8*lc+7
    int n0 = blockIdx.x * BM;
    if (t < 128) { ss1[t] = 0.f; ss2[t] = 0.f; }
    __syncthreads();

    // ---- gather phase: wave w builds sA rows w*16 .. w*16+15 ----
    for (int i = 0; i < 16; ++i) {
        int node = n0 + w * 16 + i;
        float ag[8];
        #pragma unroll
        for (int j = 0; j < 8; ++j) ag[j] = 0.f;
        if (node < nN) {
            int start = offs[node];
            int end = start + degI[node];
            for (int jb = start; jb < end; jb += 16) {
                int eidl = elist[jb + lc];          // lanes 0-15 hold 16 edge ids (padded read)
                #pragma unroll
                for (int q = 0; q < 4; ++q) {
                    int e = jb + (lg << 2) + q;
                    int s = __shfl(eidl, (lg << 2) + q);
                    if (e < end) {
                        uint4 p = *reinterpret_cast<const uint4*>(
                            heatS + ((size_t)s << 7) + (lc << 3));
                        ag[0] += __uint_as_float(p.x << 16);
                        ag[1] += __uint_as_float(p.x & 0xFFFF0000u);
                        ag[2] += __uint_as_float(p.y << 16);
                        ag[3] += __uint_as_float(p.y & 0xFFFF0000u);
                        ag[4] += __uint_as_float(p.z << 16);
                        ag[5] += __uint_as_float(p.z & 0xFFFF0000u);
                        ag[6] += __uint_as_float(p.w << 16);
                        ag[7] += __uint_as_float(p.w & 0xFFFF0000u);
                    }
                }
            }
        }
        #pragma unroll
        for (int j = 0; j < 8; ++j) {
            ag[j] += __shfl_xor(ag[j], 16);
            ag[j] += __shfl_xor(ag[j], 32);
        }
        if (lg == 0) {
            uint4 o;
            o.x = f2bf(ag[0]) | (f2bf(ag[1]) << 16);
            o.y = f2bf(ag[2]) | (f2bf(ag[3]) << 16);
            o.z = f2bf(ag[4]) | (f2bf(ag[5]) << 16);
            o.w = f2bf(ag[6]) | (f2bf(ag[7]) << 16);
            *reinterpret_cast<uint4*>(&sA[(w * 16 + i) * 136 + lc * 8]) = o;
        }
    }
    // each wave reads only rows it wrote -> per-wave lgkmcnt ordering suffices, no barrier

    // ---- MFMA phase ----
    int lr = l & 15;
    int lq = l >> 4;
    int rowbase = n0 + w * 16;
    f32x4 acc[8];
    #pragma unroll
    for (int ct = 0; ct < 8; ++ct) acc[ct] = (f32x4){0.f, 0.f, 0.f, 0.f};
    #pragma unroll
    for (int ks = 0; ks < 4; ++ks) {
        bf16x8 afrag = *reinterpret_cast<const bf16x8*>(
            &sA[(w * 16 + lr) * 136 + ks * 32 + lq * 8]);
        #pragma unroll
        for (int ct = 0; ct < 8; ++ct) {
            bf16x8 bfrag = *reinterpret_cast<const bf16x8*>(
                WtB + (ct * 16 + lr) * D + ks * 32 + lq * 8);
            acc[ct] = __builtin_amdgcn_mfma_f32_16x16x32_bf16(afrag, bfrag, acc[ct], 0, 0, 0);
        }
    }

    // ---- epilogue: row-scale, bias, PReLU, store, stats ----
    float alpha = a1[0];
    float s4[4];
    int nv[4];
    #pragma unroll
    for (int j = 0; j < 4; ++j) {
        int n = rowbase + lq * 4 + j;
        nv[j] = n;
        s4[j] = (n < nN) ? rsqrtf((float)max(degI[n], 1)) : 0.f;
    }
    #pragma unroll
    for (int ct = 0; ct < 8; ++ct) {
        int f = ct * 16 + lr;
        float bias = b[f];
        float p1 = 0.f, p2 = 0.f;
        #pragma unroll
        for (int j = 0; j < 4; ++j) {
            if (nv[j] < nN) {
                float v = acc[ct][j] * s4[j] + bias;
                v = v > 0.f ? v : alpha * v;
                h[((size_t)nv[j] << 7) + f] = v;
                p1 += v; p2 += v * v;
            }
        }
        atomicAdd(&ss1[f], p1);
        atomicAdd(&ss2[f], p2);
    }
    __syncthreads();
    if (t < 128) {
        int slot = blockIdx.x & 15;
        atomicAdd(&sums[slot * D + t], ss1[t]);
        atomicAdd(&sumsq[slot * D + t], ss2[t]);
    }
}

__global__ void k_finalize(
        const float* __restrict__ sums, const float* __restrict__ sumsq,
        const float* __restrict__ gamma, const float* __restrict__ beta,
        float* __restrict__ stats, int nN) {
    int f = threadIdx.x;
    float s1 = 0.f, s2 = 0.f;
    #pragma unroll
    for (int i = 0; i < 16; ++i) { s1 += sums[i * D + f]; s2 += sumsq[i * D + f]; }
    float inv_n = 1.0f / (float)nN;
    float mean = s1 * inv_n;
    float var = s2 * inv_n - mean * mean;
    float inv = rsqrtf(var + 1e-5f);
    float sc = gamma[f] * inv;
    stats[f] = sc;
    stats[D + f] = beta[f] - mean * sc;
}

__global__ __launch_bounds__(256) void k_apply(
        float* __restrict__ h, const float* __restrict__ stats,
        const float* __restrict__ a2, int total4) {
    int i = blockIdx.x * 256 + threadIdx.x;
    if (i >= total4) return;
    float alpha = a2[0];
    int c = (i & 31) << 2;
    float4 v = *reinterpret_cast<const float4*>(h + (size_t)i * 4);
    float4 sc = *reinterpret_cast<const float4*>(stats + c);
    float4 sh = *reinterpret_cast<const float4*>(stats + D + c);
    float4 r;
    r.x = v.x * sc.x + sh.x; r.x = r.x > 0.f ? r.x : alpha * r.x;
    r.y = v.y * sc.y + sh.y; r.y = r.y > 0.f ? r.y : alpha * r.y;
    r.z = v.z * sc.z + sh.z; r.z = r.z > 0.f ? r.z : alpha * r.z;
    r.w = v.w * sc.w + sh.w; r.w = r.w > 0.f ? r.w : alpha * r.w;
    *reinterpret_cast<float4*>(h + (size_t)i * 4) = r;
}

extern "C" void kernel_launch(void* const* d_in, const int* in_sizes, int n_in,
                              void* d_out, int out_size, void* d_ws, size_t ws_size,
                              hipStream_t stream) {
    const float* heat  = (const float*)d_in[0];
    const float* W     = (const float*)d_in[1];
    const float* b     = (const float*)d_in[2];
    const float* a1    = (const float*)d_in[3];
    const float* gamma = (const float*)d_in[4];
    const float* beta  = (const float*)d_in[5];
    const float* a2    = (const float*)d_in[6];
    const int*   src   = (const int*)d_in[7];
    const int*   dst   = (const int*)d_in[8];

    const int nN = in_sizes[0] / D;
    const int nE = in_sizes[7];
    const int NBK = (nN + BW - 1) >> BSH;
    const int nEB = (nE + 4095) / 4096;

    char* ws = (char*)d_ws;
    size_t o = 0;
    auto alloc = [&](size_t bytes) { size_t r = o; o = (o + bytes + 255) & ~(size_t)255; return r; };
    int*   bcntD = (int*)(ws + alloc(256 * 4));
    int*   bcntS = (int*)(ws + alloc(256 * 4));
    float* sums  = (float*)(ws + alloc(16 * D * 4));
    float* sumsq = (float*)(ws + alloc(16 * D * 4));
    size_t zero_end = o;
    int*   bbaseD = (int*)(ws + alloc(257 * 4));
    int*   bcurD  = (int*)(ws + alloc(256 * 4));
    int*   bbaseS = (int*)(ws + alloc(257 * 4));
    int*   bcurS  = (int*)(ws + alloc(256 * 4));
    float* stats  = (float*)(ws + alloc(2 * D * 4));
    unsigned short* WtB = (unsigned short*)(ws + alloc((size_t)D * D * 2));
    int*   degO   = (int*)(ws + alloc((size_t)nN * 4));
    int*   degI   = (int*)(ws + alloc((size_t)nN * 4));
    int*   offs   = (int*)(ws + alloc((size_t)nN * 4));
    int*   elist  = (int*)(ws + alloc(((size_t)nE + 64) * 4));  // +pad for overread
    unsigned int*   pairsD = (unsigned int*)(ws + alloc((size_t)nE * 4));
    unsigned short* srcL   = (unsigned short*)(ws + alloc((size_t)nE * 2));
    unsigned short* heatS  = (unsigned short*)(ws + alloc((size_t)nN * D * 2));
    float* h = (float*)d_out;

    hipMemsetAsync(ws, 0, zero_end, stream);

    k_count<<<nEB, 256, 0, stream>>>(src, dst, bcntD, bcntS, nE, NBK);
    k_bscan2<<<1, 256, 0, stream>>>(bcntD, bcntS, bbaseD, bcurD, bbaseS, bcurS, NBK, nE);
    k_pairs<<<nEB, 256, 0, stream>>>(src, dst, bcurD, bcurS, pairsD, srcL, nE);
    k_binD<<<NBK, 512, 0, stream>>>(pairsD, bbaseD, degI, offs, elist, nN);
    k_binO<<<NBK, 512, 0, stream>>>(srcL, bbaseS, degO, nN);
    k_prepW<<<(D * D + 255) / 256, 256, 0, stream>>>(W, WtB);
    k_prep2<<<(nN * 32 + 255) / 256, 256, 0, stream>>>(heat, degO, heatS, nN);
    k_fused<<<(nN + BM - 1) / BM, 256, 0, stream>>>(
        heatS, elist, offs, degI, WtB, b, a1, h, sums, sumsq, nN);
    k_finalize<<<1, 128, 0, stream>>>(sums, sumsq, gamma, beta, stats, nN);
    k_apply<<<(nN * (D / 4) + 255) / 256, 256, 0, stream>>>(h, stats, a2, nN * (D / 4));
}